// Round 9
// baseline (535.732 us; speedup 1.0000x reference)
//
#include <hip/hip_runtime.h>
#include <hip/hip_bf16.h>

// BayesianKAN: 3 layers of  out[b,o] = sum_{i,k} B-spline-basis(x[b,i])[k] * cm[o,i,k]
// == GEMM (M=8192, N=OUT, K=IN*16) with generated A-operand, plus KL scalar.
// Numerics (validated R4-R8): f16 MFMA; L0 2-term A-split, L1/L2 1-term.
// R9: latency pipeline. R8 was latency-chain bound (wall 10.4k cyc/kstep vs
// 1.2k MFMA): act load + B drain had zero prefetch slack. Now BK=32,
// double-buffered B (16KB x2), single A (8KB [+8 lo]); B(k+1) issued right
// after barrier2(k) (slack = full MFMA phase ~1.8k cyc before its draining
// barrier), act(k+2) issued inside MFMA phase (slack = full kstep), spline
// (k+1) computed between barriers from regs. All LDS frag ops base+lane*16,
// 0 conflicts. Races excluded: B(k+2)->buf issues only after barrier2(k+1),
// which implies every wave's MFMA(k) ds_reads already drained (lgkmcnt at
// barrier arrival).

typedef __attribute__((ext_vector_type(8))) _Float16 f16x8;  // 8 f16 in 4 VGPRs
typedef __attribute__((ext_vector_type(4))) float float4v;   // MFMA accumulator
typedef unsigned short ushort_t;

#define GLOBAL_AS __attribute__((address_space(1)))
#define LDS_AS __attribute__((address_space(3)))

__device__ __forceinline__ void async_copy16(const void* g, void* l) {
  __builtin_amdgcn_global_load_lds((const GLOBAL_AS unsigned int*)g,
                                   (LDS_AS unsigned int*)l, 16, 0, 0);
}

__device__ __forceinline__ ushort_t f2h(float f) {
  _Float16 h = (_Float16)f;                 // RTE
  return *(ushort_t*)&h;
}
__device__ __forceinline__ float h2f(ushort_t u) {
  return (float)*(_Float16*)&u;
}

// Cubic B-spline (n_basis=16, clamped uniform knots: 13 cells of width 1/13).
__device__ __forceinline__ void bspline_w4(float x, int& k0, float w[4]) {
  const float XMAX = 1.0f - 1e-6f;
  float xe = fminf(fmaxf(x, 0.0f), XMAX);
  int cell = (int)(xe * 13.0f);
  cell = cell > 12 ? 12 : cell;
  k0 = cell;
  int j = cell + 3;                 // knot span, 3..15
  const float s = 1.0f / 13.0f;
  int cjm2 = max(j - 5, 0);
  int cjm1 = max(j - 4, 0);
  int cj   = j - 3;
  int cj1  = j - 2;
  int cj2  = min(j - 1, 13);
  int cj3  = min(j, 13);
  float tjm2 = cjm2 * s, tjm1 = cjm1 * s, tj = cj * s;
  float tj1 = cj1 * s, tj2 = cj2 * s, tj3 = cj3 * s;
  float left1 = xe - tj, left2 = xe - tjm1, left3 = xe - tjm2;
  float right1 = tj1 - xe, right2 = tj2 - xe, right3 = tj3 - xe;
#define INV3(d) ((d) == 1 ? 13.0f : ((d) == 2 ? 6.5f : (13.0f / 3.0f)))
  float i10 = INV3(cj1 - cj);
  float i20 = INV3(cj1 - cjm1), i21 = INV3(cj2 - cj);
  float i30 = INV3(cj1 - cjm2), i31 = INV3(cj2 - cjm1), i32 = INV3(cj3 - cj);
#undef INV3
  float temp = i10;
  float N0 = right1 * temp;
  float N1 = left1 * temp;
  temp = N0 * i20;
  N0 = right1 * temp;
  float saved = left2 * temp;
  temp = N1 * i21;
  N1 = saved + right2 * temp;
  float N2 = left1 * temp;
  temp = N0 * i30;
  N0 = right1 * temp;
  saved = left3 * temp;
  temp = N1 * i31;
  N1 = saved + right2 * temp;
  saved = left2 * temp;
  temp = N2 * i32;
  N2 = saved + right3 * temp;
  float N3 = left1 * temp;
  w[0] = N0; w[1] = N1; w[2] = N2; w[3] = N3;
}

// Build the 16-f16 basis row (8 dwords) for one feature in registers.
__device__ __forceinline__ void compose16(const float w[4], int k0, unsigned u[8]) {
  unsigned h0 = f2h(w[0]), h1 = f2h(w[1]), h2 = f2h(w[2]), h3 = f2h(w[3]);
  int e = k0 >> 1;
  bool odd = (k0 & 1) != 0;
  unsigned a = odd ? (h0 << 16) : (h0 | (h1 << 16));
  unsigned b = odd ? (h1 | (h2 << 16)) : (h2 | (h3 << 16));
  unsigned c = odd ? (unsigned)h3 : 0u;
#pragma unroll
  for (int j = 0; j < 8; ++j)
    u[j] = (j == e) ? a : (j == e + 1) ? b : (j == e + 2) ? c : 0u;
}

// Block 128(M) x 256(N), BK=32 (2 feats x 16 basis). 4 waves 2x2; wave tile
// 64x128 (4x8 frags of f32_16x16x32_f16). A and B in MFMA-fragment-layout LDS.
// blockIdx.z = split-K; partials atomicAdd into pre-zeroed outp.
template <bool SPLIT_A>
__global__ __launch_bounds__(256, 2) void kan_layer(
    const float* __restrict__ act, const ushort_t* __restrict__ Bsw,
    float* __restrict__ outp, int IN, int OUT) {
  const int K = IN * 16;
  const int KC = K >> 3;                       // k-chunks of 8
  __shared__ ushort_t Bt[2][16 * 512];         // 2 x 16KB: 16 n-tile frags
  __shared__ ushort_t Ahi[8 * 512];            // 8KB: 8 m-tile frags
  __shared__ ushort_t Alo[SPLIT_A ? 8 * 512 : 1];

  const int tid = threadIdx.x;
  const int lane = tid & 63;
  const int wv = tid >> 6;
  const int wm = wv >> 1, wn = wv & 1;
  const int quad = lane >> 4, l15 = lane & 15;
  const int b0 = blockIdx.x * 128;
  const int n0 = blockIdx.y * 256;
  const int tbase = n0 >> 4;                   // global B n-tile base

  float4v acc[4][8];
#pragma unroll
  for (int a = 0; a < 4; a++)
#pragma unroll
    for (int b = 0; b < 8; b++) acc[a][b] = (float4v)0.0f;

  const int sr = tid & 127;                    // staging row 0..127
  const int sf = tid >> 7;                     // staging feat 0/1
  // A write address (frag layout): quads 2*sf, 2*sf+1 of m-tile sr>>4
  const int awoff = (sr >> 4) * 512 + sf * 256 + (sr & 15) * 8;  // ushorts

  const int nsteps = K / 32;
  const int chunk = nsteps / gridDim.z;        // exact for all configs
  const int kbeg = blockIdx.z * chunk;
  const int kend = kbeg + chunk;

#define ISSUE_B(kk, buf)                                                      \
  {                                                                           \
    _Pragma("unroll") for (int j = 0; j < 4; ++j) {                           \
      int w = wv * 4 + j;                                                     \
      size_t goff =                                                           \
          ((size_t)(tbase + w) * KC + (size_t)(kk) * 4) * 128 + lane * 8;     \
      async_copy16(&Bsw[goff], &Bt[buf][w * 512 + lane * 8]);                 \
    }                                                                         \
  }

  // ---- prologue ----
  int k0c; float wc[4];
  {
    float x0 = act[(size_t)(b0 + sr) * IN + kbeg * 2 + sf];
    bspline_w4(x0, k0c, wc);
  }
  ISSUE_B(kbeg, 0);
  float xnext = (kbeg + 1 < kend)
                    ? act[(size_t)(b0 + sr) * IN + (kbeg + 1) * 2 + sf]
                    : 0.0f;

  for (int k = kbeg; k < kend; ++k) {
    const int buf = (k - kbeg) & 1;

    __syncthreads();  // bar1: prev MFMA frag-reads done; drains B(k) (landed)

    // ---- A-write(k) from spline regs (frag layout, conflict-free b128) ----
    {
      unsigned u[8];
      compose16(wc, k0c, u);
      *(uint4*)&Ahi[awoff]       = make_uint4(u[0], u[1], u[2], u[3]);
      *(uint4*)&Ahi[awoff + 128] = make_uint4(u[4], u[5], u[6], u[7]);
      if (SPLIT_A) {
        float wl[4];
#pragma unroll
        for (int t = 0; t < 4; ++t) wl[t] = wc[t] - h2f(f2h(wc[t]));
        compose16(wl, k0c, u);
        *(uint4*)&Alo[awoff]       = make_uint4(u[0], u[1], u[2], u[3]);
        *(uint4*)&Alo[awoff + 128] = make_uint4(u[4], u[5], u[6], u[7]);
      }
    }

    // ---- spline(k+1) from prefetched act (consumes xnext before bar2) ----
    bspline_w4(xnext, k0c, wc);

    __syncthreads();  // bar2: A(k) visible; B(k) long since drained

    // ---- issue next-kstep loads: full MFMA phase of slack ----
    if (k + 1 < kend) ISSUE_B(k + 1, buf ^ 1);
    if (k + 2 < kend)
      xnext = act[(size_t)(b0 + sr) * IN + (k + 2) * 2 + sf];

    // ---- fragment reads (base+lane*16, conflict-free) + MFMA ----
    {
      f16x8 ah[4], al[4], bh[8];
#pragma unroll
      for (int mt = 0; mt < 4; ++mt) {
        int fb = (wm * 4 + mt) * 512 + lane * 8;
        ah[mt] = *(const f16x8*)&Ahi[fb];
        if (SPLIT_A) al[mt] = *(const f16x8*)&Alo[fb];
      }
#pragma unroll
      for (int nt = 0; nt < 8; ++nt)
        bh[nt] = *(const f16x8*)&Bt[buf][(wn * 8 + nt) * 512 + lane * 8];
#pragma unroll
      for (int mt = 0; mt < 4; ++mt)
#pragma unroll
        for (int nt = 0; nt < 8; ++nt) {
          if (SPLIT_A)
            acc[mt][nt] = __builtin_amdgcn_mfma_f32_16x16x32_f16(al[mt], bh[nt], acc[mt][nt], 0, 0, 0);
          acc[mt][nt] = __builtin_amdgcn_mfma_f32_16x16x32_f16(ah[mt], bh[nt], acc[mt][nt], 0, 0, 0);
        }
    }
  }
#undef ISSUE_B

  // ---- epilogue: C/D layout col=lane&15, row=quad*4+reg; split-K atomics ----
#pragma unroll
  for (int mt = 0; mt < 4; ++mt)
#pragma unroll
    for (int nt = 0; nt < 8; ++nt) {
      int col = n0 + wn * 128 + nt * 16 + l15;
#pragma unroll
      for (int r = 0; r < 4; ++r) {
        int row = b0 + wm * 64 + mt * 16 + quad * 4 + r;
        atomicAdd(&outp[(size_t)row * OUT + col], acc[mt][nt][r]);
      }
    }
}

// KL accumulation + f16 conversion + fragment-order swizzle, one pass over cm/lv.
// Group = 8 consecutive k of one output row o: dest Bsw[o/16][k/8][o%16][8].
__global__ __launch_bounds__(256) void kl_convert(
    const float* __restrict__ cm, const float* __restrict__ lv,
    ushort_t* __restrict__ bsw, int G /* = IN*2 groups per row */,
    long long ngroups, float* __restrict__ klout) {
  long long i = (long long)blockIdx.x * blockDim.x + threadIdx.x;
  const long long stride = (long long)gridDim.x * blockDim.x;
  float s = 0.0f;
  for (; i < ngroups; i += stride) {
    int o = (int)(i / G);
    int kc = (int)(i - (long long)o * G);
    const float* cp = &cm[i * 8];
    const float* lp = &lv[i * 8];
    unsigned pk[4];
#pragma unroll
    for (int t = 0; t < 4; ++t) {
      float c0 = cp[2 * t], c1 = cp[2 * t + 1];
      float l0 = lp[2 * t], l1 = lp[2 * t + 1];
      pk[t] = (unsigned)f2h(c0) | ((unsigned)f2h(c1) << 16);
      s += 0.5f * (__expf(l0) + c0 * c0 - 1.0f - l0);
      s += 0.5f * (__expf(l1) + c1 * c1 - 1.0f - l1);
    }
    uint4 v; v.x = pk[0]; v.y = pk[1]; v.z = pk[2]; v.w = pk[3];
    size_t doff = (((size_t)(o >> 4) * G + kc) * 16 + (o & 15)) * 8;
    *(uint4*)&bsw[doff] = v;
  }
#pragma unroll
  for (int off = 32; off > 0; off >>= 1) s += __shfl_down(s, off, 64);
  __shared__ float red[4];
  int wvi = threadIdx.x >> 6;
  if ((threadIdx.x & 63) == 0) red[wvi] = s;
  __syncthreads();
  if (threadIdx.x == 0)
    atomicAdd(klout, red[0] + red[1] + red[2] + red[3]);
}

extern "C" void kernel_launch(void* const* d_in, const int* in_sizes, int n_in,
                              void* d_out, int out_size, void* d_ws, size_t ws_size,
                              hipStream_t stream) {
  const float* x   = (const float*)d_in[0];
  const float* cm0 = (const float*)d_in[1];
  const float* lv0 = (const float*)d_in[2];
  const float* cm1 = (const float*)d_in[3];
  const float* lv1 = (const float*)d_in[4];
  const float* cm2 = (const float*)d_in[5];
  const float* lv2 = (const float*)d_in[6];

  float* out = (float*)d_out;                       // (8192*256) out + 1 KL
  float* klp = out + (size_t)8192 * 256;

  // ws layout (48 MB): acts 2x16MB, swizzled f16 weights 16MB
  char* ws = (char*)d_ws;
  float*    act1 = (float*)(ws);                               // 8192*512 f32
  float*    act2 = (float*)(ws + ((size_t)16 << 20));          // 8192*512 f32
  ushort_t* b0sw = (ushort_t*)(ws + ((size_t)32 << 20));       // 512*256*16 f16
  ushort_t* b1sw = (ushort_t*)(ws + ((size_t)36 << 20));       // 512*512*16 f16
  ushort_t* b2sw = (ushort_t*)(ws + ((size_t)44 << 20));       // 256*512*16 f16

  // zero split-K accumulation targets (act1+act2 contiguous; d_out incl KL)
  hipMemsetAsync(ws, 0, (size_t)32 << 20, stream);
  hipMemsetAsync(d_out, 0, (size_t)out_size * sizeof(float), stream);

  kl_convert<<<2048, 256, 0, stream>>>(cm0, lv0, b0sw, 256 * 2, 512LL * 256 * 2, klp);
  kl_convert<<<2048, 256, 0, stream>>>(cm1, lv1, b1sw, 512 * 2, 512LL * 512 * 2, klp);
  kl_convert<<<2048, 256, 0, stream>>>(cm2, lv2, b2sw, 512 * 2, 256LL * 512 * 2, klp);

  // 512 blocks/layer -> 2 blocks/CU. LDS: L0 48KB, L1/L2 40KB.
  kan_layer<true ><<<dim3(64, 2, 4), 256, 0, stream>>>(x,    b0sw, act1, 256, 512);
  kan_layer<false><<<dim3(64, 2, 4), 256, 0, stream>>>(act1, b1sw, act2, 512, 512);
  kan_layer<false><<<dim3(64, 1, 8), 256, 0, stream>>>(act2, b2sw, out,  512, 256);
}